// Round 1
// baseline (137.990 us; speedup 1.0000x reference)
//
#include <hip/hip_runtime.h>

typedef unsigned short u16;
typedef __attribute__((ext_vector_type(4))) unsigned short u16x4;
typedef __attribute__((ext_vector_type(8))) unsigned short u16x8;
typedef __attribute__((ext_vector_type(4))) float f32x4;
typedef __attribute__((ext_vector_type(16))) float f32x16;

// Sizes (fixed by problem): N=256 S=32 M=32 E=32 B=64 N_IN=16
// ws layout: hT bf16 [2048][256] @0 (1MB); EMT bf16 [8192][256] @1MB (4MB);
//            Wf5 bf16 [32][1024] @5MB (64KB); bterm f32 [64][32] @5MB+64KB (8KB);
//            msgs f32 [64][256][32] @5MB+72KB (2MB)

__device__ __forceinline__ u16 f2bf(float x){
  unsigned u = __builtin_bit_cast(unsigned, x);
  u += 0x7FFFu + ((u >> 16) & 1u);
  return (u16)(u >> 16);
}

__device__ __forceinline__ void mfma3232(f32x16& acc, u16x8 a, u16x8 b){
  asm volatile("v_mfma_f32_32x32x16_bf16 %0, %1, %2, %0" : "+v"(acc) : "v"(a), "v"(b));
}
__device__ __forceinline__ void mfma1616(f32x4& acc, u16x8 a, u16x8 b){
  asm volatile("v_mfma_f32_16x16x32_bf16 %0, %1, %2, %0" : "+v"(acc) : "v"(a), "v"(b));
}

// ---------- P1: hT[(b*32+s)*256 + i] = bf16(h[b,i,s]) ----------
__global__ __launch_bounds__(256) void k_ht(const float* __restrict__ inputs,
                                            const float* __restrict__ init,
                                            u16* __restrict__ hT){
  int tid = blockIdx.x*256 + threadIdx.x;      // 131072 threads
  int base = tid*4;
  int r = base >> 8;           // b*32+s
  int i0 = base & 255;
  int b = r >> 5, s = r & 31;
  u16x4 v;
#pragma unroll
  for (int q=0;q<4;++q){
    int i = i0 + q;
    float x = (i < 16) ? inputs[(b*16 + i)*32 + s] : init[i*32 + s];
    v[q] = f2bf(x);
  }
  *(u16x4*)(hT + base) = v;
}

// ---------- P2: EMT[c*256 + i] = bf16(EM[i*8192 + c])  (LDS-tiled transpose) ----------
__global__ __launch_bounds__(256) void k_emt(const float* __restrict__ EM, u16* __restrict__ EMT){
  __shared__ float tl[64*65];
  int t = threadIdx.x;
  int i0 = blockIdx.y*64, c0 = blockIdx.x*64;
#pragma unroll
  for (int p=0;p<4;++p){
    int ri = p*16 + (t>>4);
    int c4 = (t&15)*4;
    f32x4 v = *(const f32x4*)(EM + (i0+ri)*8192 + c0 + c4);
#pragma unroll
    for (int q=0;q<4;++q) tl[ri*65 + c4 + q] = v[q];
  }
  __syncthreads();
#pragma unroll
  for (int p=0;p<4;++p){
    int rc = p*16 + (t>>4);
    int i4 = (t&15)*4;
    u16x4 o;
#pragma unroll
    for (int q=0;q<4;++q) o[q] = f2bf(tl[(i4+q)*65 + rc]);
    *(u16x4*)(EMT + (c0+rc)*256 + i0 + i4) = o;
  }
}

// ---------- P3: Wf5[m*1024 + s*32 + e] = bf16(Wf[e*1024 + m*32 + s]) ----------
__global__ __launch_bounds__(256) void k_wf5(const float* __restrict__ Wf, u16* __restrict__ Wf5){
  int o = (blockIdx.x*256 + threadIdx.x)*4;    // 32 blocks
  int m = o >> 10, rem = o & 1023, s = rem >> 5, e0 = rem & 31;
  u16x4 v;
#pragma unroll
  for (int q=0;q<4;++q) v[q] = f2bf(Wf[(e0+q)*1024 + m*32 + s]);
  *(u16x4*)(Wf5 + o) = v;
}

// ---------- P4: bterm[b][m] = sum_s (sum_i h[b,i,s]) * bf[m*32+s] ----------
__global__ __launch_bounds__(256) void k_bterm(const float* __restrict__ inputs,
                                               const float* __restrict__ init,
                                               const float* __restrict__ bf,
                                               float* __restrict__ bterm){
  __shared__ float red[8][32];
  __shared__ float hsum[32];
  int b = blockIdx.x, t = threadIdx.x;
  int g = t >> 5, s = t & 31;
  float acc = 0.f;
  for (int c=0;c<32;++c){
    int i = c*8 + g;
    acc += (i < 16) ? inputs[(b*16 + i)*32 + s] : init[i*32 + s];
  }
  red[g][s] = acc;
  __syncthreads();
  if (t < 32){
    float v = 0.f;
#pragma unroll
    for (int gg=0;gg<8;++gg) v += red[gg][t];
    hsum[t] = v;
  }
  __syncthreads();
  if (t < 32){
    float v = 0.f;
    for (int s2=0;s2<32;++s2) v += hsum[s2] * bf[t*32 + s2];
    bterm[b*32 + t] = v;
  }
}

// ---------- G1: T-GEMM (64x256 tile, K=256) + fused Wf epilogue -> messages ----------
__global__ __launch_bounds__(256) void k_gemm(const u16* __restrict__ hT, const u16* __restrict__ EMT,
                                              const u16* __restrict__ Wf5, const float* __restrict__ bterm,
                                              float* __restrict__ msgs){
  __shared__ char smem[81920];
  const int t = threadIdx.x, w = t >> 6, l = t & 63;
  const int rb = blockIdx.x & 31, cb = blockIdx.x >> 5;
  const int r0 = rb*64, c0 = cb*256;
  char* smA = smem;            // 64 rows x 256B (swizzled)
  char* smB = smem + 16384;    // 256 rows x 256B (swizzled)

  f32x16 acc[2][2];
#pragma unroll
  for (int a=0;a<2;++a)
#pragma unroll
    for (int bq=0;bq<2;++bq)
#pragma unroll
      for (int q=0;q<16;++q) acc[a][bq][q] = 0.f;

  for (int st=0; st<2; ++st){
    const int kk = st*128;
#pragma unroll
    for (int p=0;p<4;++p){          // stage A: 1024 x 16B chunks
      int q = p*256 + t;
      int r = q >> 4, k8 = q & 15;
      u16x8 v = *(const u16x8*)(hT + (r0+r)*256 + kk + k8*8);
      *(u16x8*)(smA + r*256 + ((k8*16) ^ ((r&15)<<4))) = v;
    }
#pragma unroll
    for (int p=0;p<16;++p){         // stage B: 4096 x 16B chunks
      int q = p*256 + t;
      int c = q >> 4, k8 = q & 15;
      u16x8 v = *(const u16x8*)(EMT + (c0+c)*256 + kk + k8*8);
      *(u16x8*)(smB + c*256 + ((k8*16) ^ ((c&15)<<4))) = v;
    }
    __syncthreads();
    const int lane31 = l & 31, kh = (l >> 5)*8;
#pragma unroll
    for (int ks=0; ks<8; ++ks){
      int kbyte = (ks*16 + kh)*2;
      u16x8 a0, a1, b0, b1;
      { int row = lane31;          a0 = *(const u16x8*)(smA + row*256 + (kbyte ^ ((row&15)<<4))); }
      { int row = 32 + lane31;     a1 = *(const u16x8*)(smA + row*256 + (kbyte ^ ((row&15)<<4))); }
      { int col = w*64 + lane31;   b0 = *(const u16x8*)(smB + col*256 + (kbyte ^ ((col&15)<<4))); }
      { int col = w*64 + 32 + lane31; b1 = *(const u16x8*)(smB + col*256 + (kbyte ^ ((col&15)<<4))); }
      mfma3232(acc[0][0], a0, b0);
      mfma3232(acc[0][1], a0, b1);
      mfma3232(acc[1][0], a1, b0);
      mfma3232(acc[1][1], a1, b1);
    }
    __syncthreads();
  }

  // write T tile (bf16) into smem[0..32KB): T[row(b,s)][col(j,e)]
  u16* T = (u16*)smem;
#pragma unroll
  for (int rbk=0;rbk<2;++rbk)
#pragma unroll
    for (int cbk=0;cbk<2;++cbk){
      int col = w*64 + cbk*32 + (l & 31);
#pragma unroll
      for (int q=0;q<16;++q){
        int row = rbk*32 + (q&3) + 8*(q>>2) + 4*(l>>5);
        T[row*256 + col] = f2bf(acc[rbk][cbk][q]);
      }
    }
  __syncthreads();

  // epilogue: D[m][(b,j)] = sum_{k=s*32+e} Wf5[m][k] * T[(b,s)][(j,e)], K split over 4 waves
  f32x4 eacc0, eacc1;
#pragma unroll
  for (int q=0;q<4;++q){ eacc0[q]=0.f; eacc1[q]=0.f; }
  {
    const int colbj = l & 15;
    const int bloc = colbj >> 3, jloc = colbj & 7;
    const int e0 = (l >> 4)*8;
#pragma unroll
    for (int ss=0; ss<8; ++ss){
      int s = w*8 + ss;
      u16x8 bf_ = *(const u16x8*)((char*)T + (bloc*32 + s)*512 + (jloc*32 + e0)*2);
      u16x8 af0 = *(const u16x8*)(Wf5 + (colbj)*1024 + s*32 + e0);
      u16x8 af1 = *(const u16x8*)(Wf5 + (16 + colbj)*1024 + s*32 + e0);
      mfma1616(eacc0, af0, bf_);
      mfma1616(eacc1, af1, bf_);
    }
  }
  float* red = (float*)(smem + 32768);   // [4 waves][2 halves][64 lanes][4]
  *(f32x4*)(red + ((w*2+0)*64 + l)*4) = eacc0;
  *(f32x4*)(red + ((w*2+1)*64 + l)*4) = eacc1;
  __syncthreads();
  const int b0g = rb*2, j0g = cb*8;
  for (int o = t; o < 512; o += 256){
    int col = o >> 5, m = o & 31;
    int hh = m >> 4, mloc = m & 15;
    int lsrc = col | ((mloc >> 2) << 4);
    int q = mloc & 3;
    float sum = 0.f;
#pragma unroll
    for (int wv=0; wv<4; ++wv) sum += red[((wv*2+hh)*64 + lsrc)*4 + q];
    int bg = b0g + (col >> 3), jg = j0g + (col & 7);
    msgs[(bg*256 + jg)*32 + m] = sum + bterm[bg*32 + m];
  }
}

// ---------- GRU: z,r,htilde,h_new + scatter outputs ----------
__global__ __launch_bounds__(256) void k_gru(const float* __restrict__ inputs, const float* __restrict__ init,
    const float* __restrict__ msgs,
    const float* __restrict__ Wz, const float* __restrict__ Uz, const float* __restrict__ bz,
    const float* __restrict__ Wr, const float* __restrict__ Ur, const float* __restrict__ br,
    const float* __restrict__ Wh, const float* __restrict__ Uh, const float* __restrict__ bh,
    float* __restrict__ out){
  __shared__ float L[6*1024 + 96];
  for (int i = threadIdx.x; i < 1024; i += 256){
    L[i] = Wz[i]; L[1024+i] = Uz[i]; L[2048+i] = Wr[i];
    L[3072+i] = Ur[i]; L[4096+i] = Wh[i]; L[5120+i] = Uh[i];
  }
  if (threadIdx.x < 32){
    L[6144+threadIdx.x] = bz[threadIdx.x];
    L[6176+threadIdx.x] = br[threadIdx.x];
    L[6208+threadIdx.x] = bh[threadIdx.x];
  }
  __syncthreads();
  const int t = threadIdx.x, s = t & 31;
  const int rowbase = blockIdx.x*64 + (t>>6)*16 + ((t>>5)&1)*8;   // 8 rows per thread-half-wave
  float mv[8], hv[8], az[8], ar[8];
#pragma unroll
  for (int j=0;j<8;++j){
    int grow = rowbase + j; int b = grow >> 8, n = grow & 255;
    mv[j] = msgs[grow*32 + s];
    hv[j] = (n < 16) ? inputs[(b*16 + n)*32 + s] : init[n*32 + s];
    az[j] = L[6144+s]; ar[j] = L[6176+s];
  }
  for (int k=0;k<32;++k){
    float wz = L[k*32+s], uz = L[1024+k*32+s], wr = L[2048+k*32+s], ur = L[3072+k*32+s];
    int src = (t & 32) | k;
#pragma unroll
    for (int j=0;j<8;++j){
      float mk = __shfl(mv[j], src, 64);
      float hk = __shfl(hv[j], src, 64);
      az[j] += mk*wz + hk*uz;
      ar[j] += mk*wr + hk*ur;
    }
  }
  float zz[8], rh[8], ah[8];
#pragma unroll
  for (int j=0;j<8;++j){
    zz[j] = 1.f/(1.f + __expf(-az[j]));
    float rr = 1.f/(1.f + __expf(-ar[j]));
    rh[j] = rr * hv[j];
    ah[j] = L[6208+s];
  }
  for (int k=0;k<32;++k){
    float wh = L[4096+k*32+s], uh = L[5120+k*32+s];
    int src = (t & 32) | k;
#pragma unroll
    for (int j=0;j<8;++j){
      float mk  = __shfl(mv[j], src, 64);
      float rhk = __shfl(rh[j], src, 64);
      ah[j] += mk*wh + rhk*uh;
    }
  }
#pragma unroll
  for (int j=0;j<8;++j){
    int grow = rowbase + j; int b = grow >> 8, n = grow & 255;
    float ht = tanhf(ah[j]);
    float hn = (1.f - zz[j])*hv[j] + zz[j]*ht;
    out[32768 + grow*32 + s] = hn;                       // h_new (output 1)
    if (n >= 240) out[(255 - n)*2048 + b*32 + s] = hn;   // outputs (output 0)
  }
}

extern "C" void kernel_launch(void* const* d_in, const int* in_sizes, int n_in,
                              void* d_out, int out_size, void* d_ws, size_t ws_size,
                              hipStream_t stream) {
  const float* inputs = (const float*)d_in[0];
  const float* init   = (const float*)d_in[1];
  const float* EM     = (const float*)d_in[2];
  const float* Wf     = (const float*)d_in[3];
  const float* bf     = (const float*)d_in[4];
  const float* Wz     = (const float*)d_in[5];
  const float* Uz     = (const float*)d_in[6];
  const float* bz     = (const float*)d_in[7];
  const float* Wr     = (const float*)d_in[8];
  const float* Ur     = (const float*)d_in[9];
  const float* br     = (const float*)d_in[10];
  const float* Wh     = (const float*)d_in[11];
  const float* Uh     = (const float*)d_in[12];
  const float* bh     = (const float*)d_in[13];
  float* out = (float*)d_out;
  char* ws = (char*)d_ws;

  u16* hT     = (u16*)ws;                                  // 1MB
  u16* EMT    = (u16*)(ws + (1u<<20));                     // 4MB
  u16* Wf5    = (u16*)(ws + (5u<<20));                     // 64KB
  float* bterm = (float*)(ws + (5u<<20) + 65536);          // 8KB
  float* msgs  = (float*)(ws + (5u<<20) + 65536 + 8192);   // 2MB

  k_ht   <<<512, 256, 0, stream>>>(inputs, init, hT);
  k_emt  <<<dim3(128,4), 256, 0, stream>>>(EM, EMT);
  k_wf5  <<<32, 256, 0, stream>>>(Wf, Wf5);
  k_bterm<<<64, 256, 0, stream>>>(inputs, init, bf, bterm);
  k_gemm <<<1024, 256, 0, stream>>>(hT, EMT, Wf5, bterm, msgs);
  k_gru  <<<256, 256, 0, stream>>>(inputs, init, msgs, Wz,Uz,bz, Wr,Ur,br, Wh,Uh,bh, out);
}

// Round 2
// 121.081 us; speedup vs baseline: 1.1396x; 1.1396x over previous
//
#include <hip/hip_runtime.h>

typedef unsigned short u16;
typedef __attribute__((ext_vector_type(4))) unsigned short u16x4;
typedef __attribute__((ext_vector_type(8))) unsigned short u16x8;
typedef __attribute__((ext_vector_type(4))) float f32x4;

// Sizes: N=256 S=32 M=32 E=32 B=64 N_IN=16
// ws: hT bf16 [2048][256] @0 (1MB); EMT bf16 [8192][256] @1MB (4MB);
//     Wf5 bf16 [32][1024] @5MB (64KB); bterm f32 [64][32] @5MB+64K (8KB);
//     wsT bf16 [6][32][32] @5MB+72K (12KB)   (WzT,UzT,WrT,UrT,WhT,UhT)

__device__ __forceinline__ u16 f2bf(float x){
  unsigned u = __builtin_bit_cast(unsigned, x);
  u += 0x7FFFu + ((u >> 16) & 1u);
  return (u16)(u >> 16);
}
__device__ __forceinline__ void mfma1616(f32x4& acc, u16x8 a, u16x8 b){
  asm volatile("v_mfma_f32_16x16x32_bf16 %0, %1, %2, %0" : "+v"(acc) : "v"(a), "v"(b));
}
__device__ __forceinline__ void gl16(const void* g, void* l){
  __builtin_amdgcn_global_load_lds((const __attribute__((address_space(1))) void*)g,
                                   (__attribute__((address_space(3))) void*)l, 16, 0, 0);
}
__device__ __forceinline__ float sigm(float x){ return 1.f/(1.f + __expf(-x)); }
__device__ __forceinline__ float tanh_f(float x){ return 1.f - 2.f/(1.f + __expf(2.f*x)); }

// ================= prep: EMT | hT | Wf5 | bterm | wsT (block-role dispatch) =================
__global__ __launch_bounds__(256) void k_prep(const float* __restrict__ inputs, const float* __restrict__ init,
    const float* __restrict__ EM, const float* __restrict__ Wf, const float* __restrict__ bfv,
    const float* __restrict__ Wz, const float* __restrict__ Uz, const float* __restrict__ Wr,
    const float* __restrict__ Ur, const float* __restrict__ Wh, const float* __restrict__ Uh,
    u16* __restrict__ hT, u16* __restrict__ EMT, u16* __restrict__ Wf5,
    float* __restrict__ bterm, u16* __restrict__ wsT){
  __shared__ float tl[64*65];
  const int bid = blockIdx.x, t = threadIdx.x;
  if (bid < 512){            // ---- EMT[c][i] = bf16(EM[i][c]) tiled transpose ----
    int bx = bid & 127, by = bid >> 7;
    int i0 = by*64, c0 = bx*64;
#pragma unroll
    for (int p=0;p<4;++p){
      int ri = p*16 + (t>>4), c4 = (t&15)*4;
      f32x4 v = *(const f32x4*)(EM + (i0+ri)*8192 + c0 + c4);
#pragma unroll
      for (int q=0;q<4;++q) tl[ri*65 + c4 + q] = v[q];
    }
    __syncthreads();
#pragma unroll
    for (int p=0;p<4;++p){
      int rc = p*16 + (t>>4), i4 = (t&15)*4;
      u16x4 o;
#pragma unroll
      for (int q=0;q<4;++q) o[q] = f2bf(tl[(i4+q)*65 + rc]);
      *(u16x4*)(EMT + (c0+rc)*256 + i0 + i4) = o;
    }
  } else if (bid < 1024){    // ---- hT[(b*32+s)][i] ----
    int base = ((bid-512)*256 + t)*4;
    int r = base >> 8, i0 = base & 255;
    int b = r >> 5, s = r & 31;
    u16x4 v;
#pragma unroll
    for (int q=0;q<4;++q){
      int i = i0 + q;
      float x = (i < 16) ? inputs[(b*16 + i)*32 + s] : init[i*32 + s];
      v[q] = f2bf(x);
    }
    *(u16x4*)(hT + base) = v;
  } else if (bid < 1056){    // ---- Wf5[m][s*32+e] = Wf[e][m*32+s] ----
    int o = ((bid-1024)*256 + t)*4;
    int m = o >> 10, rem = o & 1023, s = rem >> 5, e0 = rem & 31;
    u16x4 v;
#pragma unroll
    for (int q=0;q<4;++q) v[q] = f2bf(Wf[(e0+q)*1024 + m*32 + s]);
    *(u16x4*)(Wf5 + o) = v;
  } else if (bid < 1120){    // ---- bterm[b][m] = sum_s (sum_i h[b,i,s]) * bf[m*32+s] ----
    int b = bid - 1056;
    float* red = tl;            // [8][32]
    float* hsum = tl + 256;     // [32]
    int g = t >> 5, s = t & 31;
    float acc = 0.f;
    for (int c=0;c<32;++c){
      int i = c*8 + g;
      acc += (i < 16) ? inputs[(b*16 + i)*32 + s] : init[i*32 + s];
    }
    red[g*32 + s] = acc;
    __syncthreads();
    if (t < 32){
      float v = 0.f;
#pragma unroll
      for (int gg=0;gg<8;++gg) v += red[gg*32 + t];
      hsum[t] = v;
    }
    __syncthreads();
    if (t < 32){
      float v = 0.f;
      for (int s2=0;s2<32;++s2) v += hsum[s2] * bfv[t*32 + s2];
      bterm[b*32 + t] = v;
    }
  } else {                   // ---- wsT[g][s][k] = W_g[k][s] bf16, g: Wz,Uz,Wr,Ur,Wh,Uh ----
    const float* Ws[6] = {Wz,Uz,Wr,Ur,Wh,Uh};
    for (int idx = t; idx < 6144; idx += 256){
      int g = idx >> 10, r2 = idx & 1023, s = r2 >> 5, k = r2 & 31;
      wsT[g*1024 + s*32 + k] = f2bf(Ws[g][k*32 + s]);
    }
  }
}

// ================= mega: T-GEMM (128x128, K=256) + Wf epilogue + fused GRU =================
// grid 1024 = cb(64) * 16 + rb(16);  rows (b,s): r0=rb*128 (4 b);  cols (j,e): c0=cb*128 (4 j)
__global__ __launch_bounds__(256, 3) void k_mega(const u16* __restrict__ hT, const u16* __restrict__ EMT,
    const u16* __restrict__ Wf5, const float* __restrict__ bterm, const u16* __restrict__ wsT,
    const float* __restrict__ inputs, const float* __restrict__ init,
    const float* __restrict__ bz, const float* __restrict__ br, const float* __restrict__ bh,
    float* __restrict__ out){
  __shared__ char smem[48128];
  const int t = threadIdx.x, w = t >> 6, l = t & 63;
  const int rb = blockIdx.x & 15, cb = blockIdx.x >> 4;
  const int r0 = rb*128, c0 = cb*128;
  const int wrow = (w >> 1)*64, wcol = (w & 1)*64;

  f32x4 acc[4][4];
#pragma unroll
  for (int i=0;i<4;++i)
#pragma unroll
    for (int j=0;j<4;++j)
#pragma unroll
      for (int q=0;q<4;++q) acc[i][j][q] = 0.f;

  // ---- main GEMM: 4 stages of K=64, global_load_lds w/ pre-swizzled source ----
  for (int st=0; st<4; ++st){
    const int kk = st*64;
#pragma unroll
    for (int p=0;p<4;++p){       // A: 128 rows x 64k bf16 = 16KB, linear chunks
      int q = p*256 + t, r = q>>3, sl = q&7;
      gl16(hT + (r0 + r)*256 + kk + ((sl ^ (r&7))*8), smem + q*16);
    }
#pragma unroll
    for (int p=0;p<4;++p){       // B: 128 cols x 64k
      int q = p*256 + t, c = q>>3, sl = q&7;
      gl16(EMT + (c0 + c)*256 + kk + ((sl ^ (c&7))*8), smem + 16384 + q*16);
    }
    __syncthreads();
#pragma unroll
    for (int ks=0; ks<2; ++ks){
      const int kg = ks*4 + (l>>4);
      u16x8 af[4], bfr[4];
#pragma unroll
      for (int mf=0; mf<4; ++mf){
        int row = wrow + mf*16 + (l&15);
        af[mf] = *(const u16x8*)(smem + row*128 + ((kg ^ (row&7))<<4));
      }
#pragma unroll
      for (int nf=0; nf<4; ++nf){
        int col = wcol + nf*16 + (l&15);
        bfr[nf] = *(const u16x8*)(smem + 16384 + col*128 + ((kg ^ (col&7))<<4));
      }
#pragma unroll
      for (int mf=0; mf<4; ++mf)
#pragma unroll
        for (int nf=0; nf<4; ++nf)
          mfma1616(acc[mf][nf], af[mf], bfr[nf]);
    }
    __syncthreads();
  }

  // ---- T tile (bf16, swizzled) into smem[0..32KB) ----
#pragma unroll
  for (int mf=0;mf<4;++mf)
#pragma unroll
    for (int nf=0;nf<4;++nf){
      int colg = wcol + nf*16 + (l&15);
#pragma unroll
      for (int q=0;q<4;++q){
        int rowg = wrow + mf*16 + (l>>4)*4 + q;
        *(u16*)(smem + rowg*256 + ((colg*2) ^ ((rowg&7)<<4))) = f2bf(acc[mf][nf][q]);
      }
    }
  __syncthreads();

  // ---- epilogue: D[m][(b,j)] = sum_{s,e} Wf5[m][s*32+e]*T[(b,s)][(j,e)]; K split over waves ----
  f32x4 ea0, ea1;
#pragma unroll
  for (int q=0;q<4;++q){ ea0[q]=0.f; ea1[q]=0.f; }
  {
    const int colbj = l & 15;            // bloc*4 + jloc
    const int bloc = colbj >> 2, jloc = colbj & 3;
    const int eg = (l >> 4)*8;
#pragma unroll
    for (int ss=0; ss<8; ++ss){
      int s = w*8 + ss;
      int row = bloc*32 + s;
      u16x8 bfr = *(const u16x8*)(smem + row*256 + ((jloc*64 + eg*2) ^ ((row&7)<<4)));
      u16x8 af0 = *(const u16x8*)(Wf5 + colbj*1024 + s*32 + eg);
      u16x8 af1 = *(const u16x8*)(Wf5 + (16+colbj)*1024 + s*32 + eg);
      mfma1616(ea0, af0, bfr);
      mfma1616(ea1, af1, bfr);
    }
  }
  float* red = (float*)(smem + 32768);   // [4w][2 halves][64 lanes][4] = 8KB
  *(f32x4*)(red + ((w*2+0)*64 + l)*4) = ea0;
  *(f32x4*)(red + ((w*2+1)*64 + l)*4) = ea1;
  __syncthreads();

  // ---- cross-wave reduce -> msgs + h staged in LDS ----
  float* Lmsg = (float*)(smem + 40960);  // [16][32] f32
  u16*   Lmsgb = (u16*)(smem + 43008);   // [16][32] bf16
  float* Lh   = (float*)(smem + 44032);  // [16][32] f32
  u16*   Lhb  = (u16*)(smem + 46080);    // [16][32] bf16
  u16*   Lrh  = (u16*)(smem + 47104);    // [16][32] bf16
  for (int o = t; o < 512; o += 256){
    int row = o >> 5, m = o & 31;        // row = bloc*4+jloc
    int hh = m >> 4, mloc = m & 15;
    int lsrc = row | ((mloc >> 2) << 4);
    int q = mloc & 3;
    float sum = 0.f;
#pragma unroll
    for (int wv=0; wv<4; ++wv) sum += red[((wv*2+hh)*64 + lsrc)*4 + q];
    int bg = rb*4 + (row>>2), jg = cb*4 + (row&3);
    float mval = sum + bterm[bg*32 + m];
    Lmsg[row*32+m] = mval; Lmsgb[row*32+m] = f2bf(mval);
    float hval = (jg < 16) ? inputs[(bg*16 + jg)*32 + m] : init[jg*32 + m];
    Lh[row*32+m] = hval; Lhb[row*32+m] = f2bf(hval);
  }
  __syncthreads();

  // ---- fused GRU (wave 0 only; 12x MFMA 16x16x32) ----
  if (w == 0){
    const int rloc = l & 15;
    const int kg8 = (l >> 4)*8;
    u16x8 am = *(const u16x8*)(Lmsgb + rloc*32 + kg8);
    u16x8 ah = *(const u16x8*)(Lhb   + rloc*32 + kg8);
    u16x8 wz0 = *(const u16x8*)(wsT + 0*1024 + rloc*32 + kg8);
    u16x8 wz1 = *(const u16x8*)(wsT + 0*1024 + (16+rloc)*32 + kg8);
    u16x8 uz0 = *(const u16x8*)(wsT + 1*1024 + rloc*32 + kg8);
    u16x8 uz1 = *(const u16x8*)(wsT + 1*1024 + (16+rloc)*32 + kg8);
    u16x8 wr0 = *(const u16x8*)(wsT + 2*1024 + rloc*32 + kg8);
    u16x8 wr1 = *(const u16x8*)(wsT + 2*1024 + (16+rloc)*32 + kg8);
    u16x8 ur0 = *(const u16x8*)(wsT + 3*1024 + rloc*32 + kg8);
    u16x8 ur1 = *(const u16x8*)(wsT + 3*1024 + (16+rloc)*32 + kg8);
    u16x8 wh0 = *(const u16x8*)(wsT + 4*1024 + rloc*32 + kg8);
    u16x8 wh1 = *(const u16x8*)(wsT + 4*1024 + (16+rloc)*32 + kg8);
    u16x8 uh0 = *(const u16x8*)(wsT + 5*1024 + rloc*32 + kg8);
    u16x8 uh1 = *(const u16x8*)(wsT + 5*1024 + (16+rloc)*32 + kg8);
    f32x4 zp0,zp1,rp0,rp1,hp0,hp1;
#pragma unroll
    for (int q=0;q<4;++q){ zp0[q]=0;zp1[q]=0;rp0[q]=0;rp1[q]=0;hp0[q]=0;hp1[q]=0; }
    mfma1616(zp0, am, wz0); mfma1616(zp0, ah, uz0);
    mfma1616(zp1, am, wz1); mfma1616(zp1, ah, uz1);
    mfma1616(rp0, am, wr0); mfma1616(rp0, ah, ur0);
    mfma1616(rp1, am, wr1); mfma1616(rp1, ah, ur1);
    mfma1616(hp0, am, wh0);
    mfma1616(hp1, am, wh1);
    const int crow = (l>>4)*4, cs = l & 15;
    float bz0 = bz[cs], bz1 = bz[16+cs], br0 = br[cs], br1 = br[16+cs];
    f32x4 z0,z1;
#pragma unroll
    for (int q=0;q<4;++q){
      z0[q] = sigm(zp0[q]+bz0); z1[q] = sigm(zp1[q]+bz1);
      float r0 = sigm(rp0[q]+br0), r1 = sigm(rp1[q]+br1);
      Lrh[(crow+q)*32 + cs]    = f2bf(r0 * Lh[(crow+q)*32 + cs]);
      Lrh[(crow+q)*32 + 16+cs] = f2bf(r1 * Lh[(crow+q)*32 + 16+cs]);
    }
    u16x8 arh = *(const u16x8*)(Lrh + rloc*32 + kg8);   // same-wave LDS dep, compiler waits lgkm
    mfma1616(hp0, arh, uh0);
    mfma1616(hp1, arh, uh1);
    float bh0 = bh[cs], bh1 = bh[16+cs];
#pragma unroll
    for (int q=0;q<4;++q){
      int rw = crow + q;
      float ht0 = tanh_f(hp0[q]+bh0), ht1 = tanh_f(hp1[q]+bh1);
      float h0 = Lh[rw*32+cs], h1 = Lh[rw*32+16+cs];
      float hn0 = (1.f - z0[q])*h0 + z0[q]*ht0;
      float hn1 = (1.f - z1[q])*h1 + z1[q]*ht1;
      int bg = rb*4 + (rw>>2), jg = cb*4 + (rw&3);
      int base = 32768 + (bg*256 + jg)*32;
      out[base + cs] = hn0; out[base + 16 + cs] = hn1;
      if (jg >= 240){
        int ob = (255-jg)*2048 + bg*32;
        out[ob + cs] = hn0; out[ob + 16 + cs] = hn1;
      }
    }
  }
}

extern "C" void kernel_launch(void* const* d_in, const int* in_sizes, int n_in,
                              void* d_out, int out_size, void* d_ws, size_t ws_size,
                              hipStream_t stream) {
  const float* inputs = (const float*)d_in[0];
  const float* init   = (const float*)d_in[1];
  const float* EM     = (const float*)d_in[2];
  const float* Wf     = (const float*)d_in[3];
  const float* bfv    = (const float*)d_in[4];
  const float* Wz     = (const float*)d_in[5];
  const float* Uz     = (const float*)d_in[6];
  const float* bz     = (const float*)d_in[7];
  const float* Wr     = (const float*)d_in[8];
  const float* Ur     = (const float*)d_in[9];
  const float* br     = (const float*)d_in[10];
  const float* Wh     = (const float*)d_in[11];
  const float* Uh     = (const float*)d_in[12];
  const float* bh     = (const float*)d_in[13];
  float* out = (float*)d_out;
  char* ws = (char*)d_ws;

  u16* hT      = (u16*)ws;                                  // 1MB
  u16* EMT     = (u16*)(ws + (1u<<20));                     // 4MB
  u16* Wf5     = (u16*)(ws + (5u<<20));                     // 64KB
  float* bterm = (float*)(ws + (5u<<20) + 65536);           // 8KB
  u16* wsT     = (u16*)(ws + (5u<<20) + 65536 + 8192);      // 12KB

  k_prep<<<1121, 256, 0, stream>>>(inputs, init, EM, Wf, bfv, Wz, Uz, Wr, Ur, Wh, Uh,
                                   hT, EMT, Wf5, bterm, wsT);
  k_mega<<<1024, 256, 0, stream>>>(hT, EMT, Wf5, bterm, wsT, inputs, init, bz, br, bh, out);
}

// Round 3
// 114.324 us; speedup vs baseline: 1.2070x; 1.0591x over previous
//
#include <hip/hip_runtime.h>

typedef unsigned short u16;
typedef __attribute__((ext_vector_type(4))) unsigned short u16x4;
typedef __attribute__((ext_vector_type(8))) unsigned short u16x8;
typedef __attribute__((ext_vector_type(4))) float f32x4;

// Sizes: N=256 S=32 M=32 E=32 B=64 N_IN=16
// ws: hT bf16 [2048][256] @0 (1MB); EMT bf16 [8192][256] @1MB (4MB);
//     Wf5 bf16 [32][1024] @5MB (64KB); bterm f32 [64][32] @5MB+64K (8KB);
//     wsT bf16 [6][32][32] @5MB+72K (12KB)

__device__ __forceinline__ u16 f2bf(float x){
  unsigned u = __builtin_bit_cast(unsigned, x);
  u += 0x7FFFu + ((u >> 16) & 1u);
  return (u16)(u >> 16);
}
__device__ __forceinline__ void mfma1616(f32x4& acc, u16x8 a, u16x8 b){
  asm volatile("v_mfma_f32_16x16x32_bf16 %0, %1, %2, %0" : "+v"(acc) : "v"(a), "v"(b));
}
__device__ __forceinline__ void gl16(const void* g, void* l){
  __builtin_amdgcn_global_load_lds((const __attribute__((address_space(1))) void*)g,
                                   (__attribute__((address_space(3))) void*)l, 16, 0, 0);
}
__device__ __forceinline__ float sigm(float x){ return 1.f/(1.f + __expf(-x)); }
__device__ __forceinline__ float tanh_f(float x){ return 1.f - 2.f/(1.f + __expf(2.f*x)); }

// ================= prep: EMT | hT | Wf5 | bterm | wsT (block-role dispatch) =================
__global__ __launch_bounds__(256) void k_prep(const float* __restrict__ inputs, const float* __restrict__ init,
    const float* __restrict__ EM, const float* __restrict__ Wf, const float* __restrict__ bfv,
    const float* __restrict__ Wz, const float* __restrict__ Uz, const float* __restrict__ Wr,
    const float* __restrict__ Ur, const float* __restrict__ Wh, const float* __restrict__ Uh,
    u16* __restrict__ hT, u16* __restrict__ EMT, u16* __restrict__ Wf5,
    float* __restrict__ bterm, u16* __restrict__ wsT){
  __shared__ float tl[64*65];
  const int bid = blockIdx.x, t = threadIdx.x;
  if (bid < 512){            // ---- EMT[c][i] = bf16(EM[i][c]) tiled transpose ----
    int bx = bid & 127, by = bid >> 7;
    int i0 = by*64, c0 = bx*64;
#pragma unroll
    for (int p=0;p<4;++p){
      int ri = p*16 + (t>>4), c4 = (t&15)*4;
      f32x4 v = *(const f32x4*)(EM + (i0+ri)*8192 + c0 + c4);
#pragma unroll
      for (int q=0;q<4;++q) tl[ri*65 + c4 + q] = v[q];
    }
    __syncthreads();
#pragma unroll
    for (int p=0;p<4;++p){
      int rc = p*16 + (t>>4), i4 = (t&15)*4;
      u16x4 o;
#pragma unroll
      for (int q=0;q<4;++q) o[q] = f2bf(tl[(i4+q)*65 + rc]);
      *(u16x4*)(EMT + (c0+rc)*256 + i0 + i4) = o;
    }
  } else if (bid < 1024){    // ---- hT[(b*32+s)][i] ----
    int base = ((bid-512)*256 + t)*4;
    int r = base >> 8, i0 = base & 255;
    int b = r >> 5, s = r & 31;
    u16x4 v;
#pragma unroll
    for (int q=0;q<4;++q){
      int i = i0 + q;
      float x = (i < 16) ? inputs[(b*16 + i)*32 + s] : init[i*32 + s];
      v[q] = f2bf(x);
    }
    *(u16x4*)(hT + base) = v;
  } else if (bid < 1056){    // ---- Wf5[m][s*32+e] = Wf[e][m*32+s] ----
    int o = ((bid-1024)*256 + t)*4;
    int m = o >> 10, rem = o & 1023, s = rem >> 5, e0 = rem & 31;
    u16x4 v;
#pragma unroll
    for (int q=0;q<4;++q) v[q] = f2bf(Wf[(e0+q)*1024 + m*32 + s]);
    *(u16x4*)(Wf5 + o) = v;
  } else if (bid < 1120){    // ---- bterm[b][m] = sum_s (sum_i h[b,i,s]) * bf[m*32+s] ----
    int b = bid - 1056;
    float* red = tl;            // [8][32]
    float* hsum = tl + 256;     // [32]
    int g = t >> 5, s = t & 31;
    float acc = 0.f;
    for (int c=0;c<32;++c){
      int i = c*8 + g;
      acc += (i < 16) ? inputs[(b*16 + i)*32 + s] : init[i*32 + s];
    }
    red[g*32 + s] = acc;
    __syncthreads();
    if (t < 32){
      float v = 0.f;
#pragma unroll
      for (int gg=0;gg<8;++gg) v += red[gg*32 + t];
      hsum[t] = v;
    }
    __syncthreads();
    if (t < 32){
      float v = 0.f;
      for (int s2=0;s2<32;++s2) v += hsum[s2] * bfv[t*32 + s2];
      bterm[b*32 + t] = v;
    }
  } else {                   // ---- wsT[g][s][k] = W_g[k][s] bf16 ----
    const float* Ws[6] = {Wz,Uz,Wr,Ur,Wh,Uh};
    for (int idx = t; idx < 6144; idx += 256){
      int g = idx >> 10, r2 = idx & 1023, s = r2 >> 5, k = r2 & 31;
      wsT[g*1024 + s*32 + k] = f2bf(Ws[g][k*32 + s]);
    }
  }
}

// ================= mega: pipelined T-GEMM (128x128, 8 K-steps of 32) + epilogue + GRU =================
// 1024 blocks, 4 blocks/CU (40KB LDS, <=128 VGPR). XCD-swizzled block ids.
__global__ __launch_bounds__(256, 4) void k_mega(const u16* __restrict__ hT, const u16* __restrict__ EMT,
    const u16* __restrict__ Wf5, const float* __restrict__ bterm, const u16* __restrict__ wsT,
    const float* __restrict__ inputs, const float* __restrict__ init,
    const float* __restrict__ bz, const float* __restrict__ br, const float* __restrict__ bh,
    float* __restrict__ out){
  __shared__ char smem[40960];   // [0,32K): 2x16KB stage bufs / T-tile; [32K,40K): red
  const int t = threadIdx.x, w = t >> 6, l = t & 63;
  const int logical = (blockIdx.x & 7)*128 + (blockIdx.x >> 3);   // XCD-contiguous cb groups
  const int rb = logical & 15, cb = logical >> 4;
  const int r0 = rb*128, c0 = cb*128;
  const int wrow = (w >> 1)*64, wcol = (w & 1)*64;

  f32x4 acc[4][4];
#pragma unroll
  for (int i=0;i<4;++i)
#pragma unroll
    for (int j=0;j<4;++j)
#pragma unroll
      for (int q=0;q<4;++q) acc[i][j][q] = 0.f;

  // stage K-step st (K=32) into buffer p: A 128x64B @ +0, B 128x64B @ +8192
  // LDS linear; global source pre-swizzled by slot u -> u ^ ((row>>1)&3)
#define STAGE(st, p) do { \
    const u16* gA = hT + r0*256 + (st)*32; \
    const u16* gB = EMT + c0*256 + (st)*32; \
    char* ba_ = smem + (p)*16384; \
    _Pragma("unroll") \
    for (int pp=0; pp<2; ++pp){ \
      int q = pp*256 + t; \
      int row_ = q >> 2, u_ = q & 3; \
      int src = row_*256 + ((u_ ^ ((row_>>1)&3))*8); \
      gl16(gA + src, ba_ + q*16); \
      gl16(gB + src, ba_ + 8192 + q*16); \
    } \
  } while(0)

  STAGE(0, 0);
  __syncthreads();
  const int lrow = l & 15;
  const int slot = ((l>>4) ^ ((lrow>>1)&3)) << 4;
#pragma unroll
  for (int st=0; st<8; ++st){
    if (st < 7) STAGE(st+1, (st+1)&1);          // issue next-step loads (overlap compute)
    const char* ba = smem + (st&1)*16384;
    u16x8 af[4];
#pragma unroll
    for (int mf=0; mf<4; ++mf){
      int row = wrow + mf*16 + lrow;
      af[mf] = *(const u16x8*)(ba + row*64 + slot);
    }
#pragma unroll
    for (int nf=0; nf<4; ++nf){
      int col = wcol + nf*16 + lrow;
      u16x8 bfr = *(const u16x8*)(ba + 8192 + col*64 + slot);
#pragma unroll
      for (int mf=0; mf<4; ++mf) mfma1616(acc[mf][nf], af[mf], bfr);
    }
    __syncthreads();                             // next-step loads landed during compute
  }
#undef STAGE

  // ---- T tile (bf16, swizzled, 128x256B) into smem[0..32K) ----
#pragma unroll
  for (int mf=0;mf<4;++mf)
#pragma unroll
    for (int nf=0;nf<4;++nf){
      int colg = wcol + nf*16 + (l&15);
#pragma unroll
      for (int q=0;q<4;++q){
        int rowg = wrow + mf*16 + (l>>4)*4 + q;
        *(u16*)(smem + rowg*256 + ((colg*2) ^ ((rowg&7)<<4))) = f2bf(acc[mf][nf][q]);
      }
    }
  __syncthreads();

  // ---- epilogue: D[m][(b,j)] = sum_{s,e} Wf5[m][s*32+e]*T[(b,s)][(j,e)]; K split over waves ----
  f32x4 ea0, ea1;
#pragma unroll
  for (int q=0;q<4;++q){ ea0[q]=0.f; ea1[q]=0.f; }
  {
    const int colbj = l & 15;            // bloc*4 + jloc
    const int bloc = colbj >> 2, jloc = colbj & 3;
    const int eg = (l >> 4)*8;
#pragma unroll
    for (int ss=0; ss<8; ++ss){
      int s = w*8 + ss;
      int row = bloc*32 + s;
      u16x8 bfr = *(const u16x8*)(smem + row*256 + ((jloc*64 + eg*2) ^ ((row&7)<<4)));
      u16x8 af0 = *(const u16x8*)(Wf5 + colbj*1024 + s*32 + eg);
      u16x8 af1 = *(const u16x8*)(Wf5 + (16+colbj)*1024 + s*32 + eg);
      mfma1616(ea0, af0, bfr);
      mfma1616(ea1, af1, bfr);
    }
  }
  float* red = (float*)(smem + 32768);   // [4w][2 halves][64 lanes][4] = 8KB
  *(f32x4*)(red + ((w*2+0)*64 + l)*4) = ea0;
  *(f32x4*)(red + ((w*2+1)*64 + l)*4) = ea1;
  __syncthreads();

  // ---- cross-wave reduce -> msgs + h staged in LDS (overlay dead T region) ----
  float* Lmsg  = (float*)(smem);          // [16][32] f32   @0     (2KB)
  u16*   Lmsgb = (u16*)(smem + 2048);     // [16][32] bf16  @2K    (1KB)
  float* Lh    = (float*)(smem + 3072);   // [16][32] f32   @3K    (2KB)
  u16*   Lhb   = (u16*)(smem + 5120);     // [16][32] bf16  @5K    (1KB)
  u16*   Lrh   = (u16*)(smem + 6144);     // [16][32] bf16  @6K    (1KB)
  for (int o = t; o < 512; o += 256){
    int row = o >> 5, m = o & 31;        // row = bloc*4+jloc
    int hh = m >> 4, mloc = m & 15;
    int lsrc = row | ((mloc >> 2) << 4);
    int q = mloc & 3;
    float sum = 0.f;
#pragma unroll
    for (int wv=0; wv<4; ++wv) sum += red[((wv*2+hh)*64 + lsrc)*4 + q];
    int bg = rb*4 + (row>>2), jg = cb*4 + (row&3);
    float mval = sum + bterm[bg*32 + m];
    Lmsg[row*32+m] = mval; Lmsgb[row*32+m] = f2bf(mval);
    float hval = (jg < 16) ? inputs[(bg*16 + jg)*32 + m] : init[jg*32 + m];
    Lh[row*32+m] = hval; Lhb[row*32+m] = f2bf(hval);
  }
  __syncthreads();

  // ---- fused GRU (wave 0; 12x MFMA 16x16x32, phased weight loads) ----
  if (w == 0){
    const int rloc = l & 15;
    const int kg8 = (l >> 4)*8;
    u16x8 am = *(const u16x8*)(Lmsgb + rloc*32 + kg8);
    u16x8 ah = *(const u16x8*)(Lhb   + rloc*32 + kg8);
    f32x4 zp0,zp1,rp0,rp1,hp0,hp1;
#pragma unroll
    for (int q=0;q<4;++q){ zp0[q]=0;zp1[q]=0;rp0[q]=0;rp1[q]=0;hp0[q]=0;hp1[q]=0; }
    {
      u16x8 wz0 = *(const u16x8*)(wsT + 0*1024 + rloc*32 + kg8);
      u16x8 wz1 = *(const u16x8*)(wsT + 0*1024 + (16+rloc)*32 + kg8);
      u16x8 uz0 = *(const u16x8*)(wsT + 1*1024 + rloc*32 + kg8);
      u16x8 uz1 = *(const u16x8*)(wsT + 1*1024 + (16+rloc)*32 + kg8);
      mfma1616(zp0, am, wz0); mfma1616(zp0, ah, uz0);
      mfma1616(zp1, am, wz1); mfma1616(zp1, ah, uz1);
    }
    {
      u16x8 wr0 = *(const u16x8*)(wsT + 2*1024 + rloc*32 + kg8);
      u16x8 wr1 = *(const u16x8*)(wsT + 2*1024 + (16+rloc)*32 + kg8);
      u16x8 ur0 = *(const u16x8*)(wsT + 3*1024 + rloc*32 + kg8);
      u16x8 ur1 = *(const u16x8*)(wsT + 3*1024 + (16+rloc)*32 + kg8);
      mfma1616(rp0, am, wr0); mfma1616(rp0, ah, ur0);
      mfma1616(rp1, am, wr1); mfma1616(rp1, ah, ur1);
    }
    {
      u16x8 wh0 = *(const u16x8*)(wsT + 4*1024 + rloc*32 + kg8);
      u16x8 wh1 = *(const u16x8*)(wsT + 4*1024 + (16+rloc)*32 + kg8);
      mfma1616(hp0, am, wh0);
      mfma1616(hp1, am, wh1);
    }
    const int crow = (l>>4)*4, cs = l & 15;
    float bz0 = bz[cs], bz1 = bz[16+cs], br0 = br[cs], br1 = br[16+cs];
    f32x4 z0,z1;
#pragma unroll
    for (int q=0;q<4;++q){
      z0[q] = sigm(zp0[q]+bz0); z1[q] = sigm(zp1[q]+bz1);
      float r0 = sigm(rp0[q]+br0), r1 = sigm(rp1[q]+br1);
      Lrh[(crow+q)*32 + cs]    = f2bf(r0 * Lh[(crow+q)*32 + cs]);
      Lrh[(crow+q)*32 + 16+cs] = f2bf(r1 * Lh[(crow+q)*32 + 16+cs]);
    }
    u16x8 arh = *(const u16x8*)(Lrh + rloc*32 + kg8);
    {
      u16x8 uh0 = *(const u16x8*)(wsT + 5*1024 + rloc*32 + kg8);
      u16x8 uh1 = *(const u16x8*)(wsT + 5*1024 + (16+rloc)*32 + kg8);
      mfma1616(hp0, arh, uh0);
      mfma1616(hp1, arh, uh1);
    }
    float bh0 = bh[cs], bh1 = bh[16+cs];
#pragma unroll
    for (int q=0;q<4;++q){
      int rw = crow + q;
      float ht0 = tanh_f(hp0[q]+bh0), ht1 = tanh_f(hp1[q]+bh1);
      float h0 = Lh[rw*32+cs], h1 = Lh[rw*32+16+cs];
      float hn0 = (1.f - z0[q])*h0 + z0[q]*ht0;
      float hn1 = (1.f - z1[q])*h1 + z1[q]*ht1;
      int bg = rb*4 + (rw>>2), jg = cb*4 + (rw&3);
      int base = 32768 + (bg*256 + jg)*32;
      out[base + cs] = hn0; out[base + 16 + cs] = hn1;
      if (jg >= 240){
        int ob = (255-jg)*2048 + bg*32;
        out[ob + cs] = hn0; out[ob + 16 + cs] = hn1;
      }
    }
  }
}

extern "C" void kernel_launch(void* const* d_in, const int* in_sizes, int n_in,
                              void* d_out, int out_size, void* d_ws, size_t ws_size,
                              hipStream_t stream) {
  const float* inputs = (const float*)d_in[0];
  const float* init   = (const float*)d_in[1];
  const float* EM     = (const float*)d_in[2];
  const float* Wf     = (const float*)d_in[3];
  const float* bfv    = (const float*)d_in[4];
  const float* Wz     = (const float*)d_in[5];
  const float* Uz     = (const float*)d_in[6];
  const float* bz     = (const float*)d_in[7];
  const float* Wr     = (const float*)d_in[8];
  const float* Ur     = (const float*)d_in[9];
  const float* br     = (const float*)d_in[10];
  const float* Wh     = (const float*)d_in[11];
  const float* Uh     = (const float*)d_in[12];
  const float* bh     = (const float*)d_in[13];
  float* out = (float*)d_out;
  char* ws = (char*)d_ws;

  u16* hT      = (u16*)ws;                                  // 1MB
  u16* EMT     = (u16*)(ws + (1u<<20));                     // 4MB
  u16* Wf5     = (u16*)(ws + (5u<<20));                     // 64KB
  float* bterm = (float*)(ws + (5u<<20) + 65536);           // 8KB
  u16* wsT     = (u16*)(ws + (5u<<20) + 65536 + 8192);      // 12KB

  k_prep<<<1121, 256, 0, stream>>>(inputs, init, EM, Wf, bfv, Wz, Uz, Wr, Ur, Wh, Uh,
                                   hT, EMT, Wf5, bterm, wsT);
  k_mega<<<1024, 256, 0, stream>>>(hT, EMT, Wf5, bterm, wsT, inputs, init, bz, br, bh, out);
}